// Round 5
// baseline (446.981 us; speedup 1.0000x reference)
//
#include <hip/hip_runtime.h>

// Stream compaction, single-pass (R10):
//   mask[i]  = accept_index[i] >= 0
//   dst[i]   = exclusive_prefix_sum(mask)[i]
//   out[dst[i]] = out_cache_loc[accept_index[i]]  for mask[i]
//   out[total..N) = 0
//
// R9 post-mortem: L2 slice-residency is unachievable (FETCH ~700MB ~= zero-
// reuse floor across occupancy 30-72%, slices 4-16MB, in-phase persistent vs
// drifting). dur == (FETCH+WRITE)/3.65 TB/s exactly -> pattern-determined
// service ceiling. R10 probes the RATE side instead of traffic:
//   - NT gather loads (evict-first / L2-fill relief; tests whether the wall
//     is per-XCD L2 fill rate vs L3 random-service rate).
//   - dummy lanes read the CURRENT slice's base line (stays slice-local,
//     broadcast-coalesced, L1-hot).
//   - 2-deep slice pipeline with counted vmcnt(16): slice s+1's 16 loads are
//     in flight while slice s commits -> removes 16 full vmcnt(0) drains.
//   - plain 4096-block launch (persistence bought nothing), bounds (256,4).
// Null result here => 786GB @ 3.65TB/s invariant = roofline for this
// algorithm; declare and stop.

#define N_TOTAL  16777216
#define BLOCK    256

#define EPT2     16
#define TILE2    (BLOCK * EPT2)        // 4096
#define NB2      (N_TOTAL / TILE2)     // 4096 tiles
#define SLICE_LG 20                    // 2^20 elements = 4 MB per slice
#define SLICES   (N_TOTAL >> SLICE_LG) // 16

typedef float vfloat4 __attribute__((ext_vector_type(4)));
typedef int   vint4   __attribute__((ext_vector_type(4)));

// ---------------- pass 0: zero the lookback state (32 KB) ----------------
__global__ __launch_bounds__(256) void k_init(unsigned long long* __restrict__ state) {
    state[blockIdx.x * 256 + threadIdx.x] = 0ULL;
}

// issue slice sl's 16 branch-free NT loads into tmp (no wait)
#define GATHER_ISSUE(sl, tmp)                                              \
    _Pragma("unroll")                                                      \
    for (int j = 0; j < EPT2; ++j) {                                       \
        const bool m_ = (int)((unsigned)v[j] >> SLICE_LG) == (sl);         \
        const int a_ = m_ ? v[j] : ((sl) << SLICE_LG);                     \
        tmp[j] = __builtin_nontemporal_load(src + a_);                     \
    }

// commit slice sl's matching elements from tmp into vals[]
#define GATHER_COMMIT(sl, tmp)                                             \
    {                                                                      \
        int o_ = off0;                                                     \
        _Pragma("unroll")                                                  \
        for (int j = 0; j < EPT2; ++j) {                                   \
            const bool acc_ = v[j] >= 0;                                   \
            const bool m_ = (int)((unsigned)v[j] >> SLICE_LG) == (sl);     \
            if (m_) vals[o_] = tmp[j];                                     \
            o_ += acc_;                                                    \
        }                                                                  \
    }

// ---------------- single fused pass ----------------
__global__ __launch_bounds__(BLOCK, 4) void k_compact(const int* __restrict__ idx,
                                                      const float* __restrict__ src,
                                                      float* __restrict__ out,
                                                      unsigned long long* __restrict__ state) {
    const int b = blockIdx.x;
    const int t = threadIdx.x;
    const int lane = t & 63, wave = t >> 6;

    __shared__ int wsum[BLOCK / 64], woff[BLOCK / 64], btotal;
    __shared__ long long sBase;
    __shared__ float vals[TILE2];

    // ---- load idx tile (NT: read-once) ----
    const vint4* p = (const vint4*)(idx + (size_t)b * TILE2 + (size_t)t * EPT2);
    int v[EPT2];
#pragma unroll
    for (int j = 0; j < EPT2 / 4; ++j) {
        vint4 q = __builtin_nontemporal_load(p + j);
        v[4 * j + 0] = q.x; v[4 * j + 1] = q.y;
        v[4 * j + 2] = q.z; v[4 * j + 3] = q.w;
    }
    int cnt = 0;
#pragma unroll
    for (int j = 0; j < EPT2; ++j) cnt += (v[j] >= 0);

    // ---- block exclusive scan of per-thread counts ----
    int x = cnt;
#pragma unroll
    for (int d = 1; d < 64; d <<= 1) {
        int y = __shfl_up(x, d);
        if (lane >= d) x += y;
    }
    if (lane == 63) wsum[wave] = x;
    __syncthreads();
    if (t == 0) {
        int s = 0;
#pragma unroll
        for (int w = 0; w < BLOCK / 64; ++w) { woff[w] = s; s += wsum[w]; }
        btotal = s;
        if (b == 0) {
            // flag 2 = PREFIX (inclusive), value in bits [2..]
            __hip_atomic_store(&state[0], ((unsigned long long)s << 2) | 2ULL,
                               __ATOMIC_RELAXED, __HIP_MEMORY_SCOPE_AGENT);
            sBase = 0;
        } else {
            // flag 1 = PARTIAL -- published BEFORE the gather phase
            __hip_atomic_store(&state[b], ((unsigned long long)s << 2) | 1ULL,
                               __ATOMIC_RELAXED, __HIP_MEMORY_SCOPE_AGENT);
        }
    }
    __syncthreads();

    const int off0 = (x - cnt) + woff[wave];   // this thread's first LDS slot

    // ---- slice-swept gather, 2-deep pipelined (issue s+1 before commit s) ----
    {
        float tA[EPT2], tB[EPT2];
        GATHER_ISSUE(0, tA);
#pragma unroll 1
        for (int s = 0; s < SLICES; s += 2) {
            GATHER_ISSUE(s + 1, tB);
            asm volatile("s_waitcnt vmcnt(16)" ::: "memory");  // tA's 16 done
            GATHER_COMMIT(s, tA);
            if (s + 2 < SLICES) {
                GATHER_ISSUE(s + 2, tA);
                asm volatile("s_waitcnt vmcnt(16)" ::: "memory"); // tB's done
            } else {
                asm volatile("s_waitcnt vmcnt(0)" ::: "memory");
            }
            GATHER_COMMIT(s + 1, tB);
        }
    }

    // ---- decoupled lookback AFTER the sweep (predecessors published) ----
    if (b > 0 && wave == 0) {
        long long excl = 0;
        int look = b - 1;
        for (;;) {
            const int pos = look - lane;          // lane 0 = nearest predecessor
            unsigned long long s = 2ULL;          // pos<0 -> fake PREFIX(0)
            if (pos >= 0)
                s = __hip_atomic_load(&state[pos], __ATOMIC_RELAXED,
                                      __HIP_MEMORY_SCOPE_AGENT);
            for (;;) {
                const bool need = (pos >= 0) && ((s & 3ULL) == 0ULL);
                if (!__any(need)) break;
                if (need) {
                    __builtin_amdgcn_s_sleep(2);  // throttle spin traffic
                    s = __hip_atomic_load(&state[pos], __ATOMIC_RELAXED,
                                          __HIP_MEMORY_SCOPE_AGENT);
                }
            }
            const unsigned long long ball = __ballot((s & 3ULL) == 2ULL);
            const int fp = ball ? (__ffsll((long long)ball) - 1) : 64;
            long long c = (lane <= fp) ? (long long)(s >> 2) : 0;
#pragma unroll
            for (int d = 32; d; d >>= 1) c += __shfl_down(c, d);
            excl += __shfl(c, 0);
            if (ball) break;                      // found a PREFIX -> done
            look -= 64;                           // whole window PARTIAL
        }
        if (lane == 0) {
            __hip_atomic_store(&state[b],
                               (((unsigned long long)(excl + btotal)) << 2) | 2ULL,
                               __ATOMIC_RELAXED, __HIP_MEMORY_SCOPE_AGENT);
            sBase = excl;
        }
    }
    __syncthreads();

    const int tot = btotal;
    const long long base = sBase;          // global exclusive accept prefix

    // ---- data write [base, base+tot): float4 NT with alignment peel ----
    {
        const long long gbeg = base, gend = base + tot;
        const long long a0 = (gbeg + 3) & ~3LL;   // first 16B-aligned idx
        const long long a1 = gend & ~3LL;         // end of vector region
        const long long hend = a0 < gend ? a0 : gend;
        for (long long g = gbeg + t; g < hend; g += BLOCK)
            __builtin_nontemporal_store(vals[(int)(g - gbeg)], out + g);
        if (a0 < gend) {
            for (long long g = a0 + (long long)t * 4; g < a1; g += (long long)BLOCK * 4) {
                const int l = (int)(g - gbeg);
                vfloat4 w = { vals[l], vals[l + 1], vals[l + 2], vals[l + 3] };
                __builtin_nontemporal_store(w, (vfloat4*)(out + g));
            }
            for (long long g = a1 + t; g < gend; g += BLOCK)
                __builtin_nontemporal_store(vals[(int)(g - gbeg)], out + g);
        }
    }

    // ---- fused tail zero via reject-prefix identity ----
    // rejects before this block: r = b*TILE2 - base; this block owes
    // rcnt = TILE2 - tot zeros at [N - r - rcnt, N - r). Union over all
    // blocks = [total, N), disjoint, never overlaps data writes.
    {
        const long long rprev = (long long)b * TILE2 - base;
        const int rcnt = TILE2 - tot;
        const long long zbeg = (long long)N_TOTAL - rprev - rcnt;
        const long long zend = (long long)N_TOTAL - rprev;
        const long long a0 = (zbeg + 3) & ~3LL;
        const long long a1 = zend & ~3LL;
        const long long hend = a0 < zend ? a0 : zend;
        for (long long g = zbeg + t; g < hend; g += BLOCK)
            __builtin_nontemporal_store(0.0f, out + g);
        if (a0 < zend) {
            const vfloat4 z = (vfloat4)(0.f);
            for (long long g = a0 + (long long)t * 4; g < a1; g += (long long)BLOCK * 4)
                __builtin_nontemporal_store(z, (vfloat4*)(out + g));
            for (long long g = a1 + t; g < zend; g += BLOCK)
                __builtin_nontemporal_store(0.0f, out + g);
        }
    }
}

extern "C" void kernel_launch(void* const* d_in, const int* in_sizes, int n_in,
                              void* d_out, int out_size, void* d_ws, size_t ws_size,
                              hipStream_t stream) {
    const int*   idx = (const int*)d_in[0];     // accept_index (int32 per harness)
    const float* src = (const float*)d_in[1];   // out_cache_loc
    float*       out = (float*)d_out;

    unsigned long long* state = (unsigned long long*)d_ws;  // NB2 x u64 = 32 KB

    k_init   <<<NB2 / 256, 256, 0, stream>>>(state);
    k_compact<<<NB2, BLOCK, 0, stream>>>(idx, src, out, state);
}